// Round 5
// baseline (20375.117 us; speedup 1.0000x reference)
//
#include <hip/hip_runtime.h>
#include <cstdint>
#include <cstddef>

#define T_SEQ 4096
#define EMB_D 512
#define HDIM 512
#define G4 2048
#define NTAGS 24
#define START_TAG 22
#define STOP_TAG 23
#define NEGV -10000.0f
#define NBLK 32      // persistent blocks per direction
#define HSLICE 16    // hidden units per block
#define SENT 0xFFFFFFFFu   // -NaN bit pattern; |h|<1 can never equal this

// ---------------------------------------------------------------------------
// 1) xg[dir][t][j] = dot(emb[sent[t]], w_ih[j]) + b_ih[j] + b_hh[j]
// ---------------------------------------------------------------------------
__global__ __launch_bounds__(256) void gemm_xg_kernel(
    const int* __restrict__ sent, const float* __restrict__ emb,
    const float* __restrict__ w_ih_f, const float* __restrict__ b_ih_f, const float* __restrict__ b_hh_f,
    const float* __restrict__ w_ih_b, const float* __restrict__ b_ih_b, const float* __restrict__ b_hh_b,
    float* __restrict__ xg)
{
    const int dir = blockIdx.z;
    const float* W  = dir ? w_ih_b : w_ih_f;
    const float* bi = dir ? b_ih_b : b_ih_f;
    const float* bh = dir ? b_hh_b : b_hh_f;
    const int m0 = blockIdx.y * 64;   // t
    const int n0 = blockIdx.x * 64;   // gate row j
    const int tid = threadIdx.x;

    __shared__ __attribute__((aligned(16))) float As[32][64];  // [k][t]
    __shared__ __attribute__((aligned(16))) float Bs[32][64];  // [k][j]

    const int lrow = tid >> 2;          // 0..63
    const int lk   = (tid & 3) * 8;     // 0,8,16,24

    const int srow = sent[m0 + lrow];
    const float* aptr = emb + (size_t)srow * EMB_D + lk;
    const float* bptr = W   + (size_t)(n0 + lrow) * EMB_D + lk;

    const int ty = tid >> 4;   // 0..15 (M)
    const int tx = tid & 15;   // 0..15 (N)

    float acc[4][4];
    #pragma unroll
    for (int i = 0; i < 4; ++i)
        #pragma unroll
        for (int j = 0; j < 4; ++j) acc[i][j] = 0.f;

    for (int kk = 0; kk < EMB_D; kk += 32) {
        float4 a0 = *(const float4*)(aptr + kk);
        float4 a1 = *(const float4*)(aptr + kk + 4);
        float4 b0 = *(const float4*)(bptr + kk);
        float4 b1 = *(const float4*)(bptr + kk + 4);
        __syncthreads();   // previous iteration's compute done before overwrite
        As[lk+0][lrow]=a0.x; As[lk+1][lrow]=a0.y; As[lk+2][lrow]=a0.z; As[lk+3][lrow]=a0.w;
        As[lk+4][lrow]=a1.x; As[lk+5][lrow]=a1.y; As[lk+6][lrow]=a1.z; As[lk+7][lrow]=a1.w;
        Bs[lk+0][lrow]=b0.x; Bs[lk+1][lrow]=b0.y; Bs[lk+2][lrow]=b0.z; Bs[lk+3][lrow]=b0.w;
        Bs[lk+4][lrow]=b1.x; Bs[lk+5][lrow]=b1.y; Bs[lk+6][lrow]=b1.z; Bs[lk+7][lrow]=b1.w;
        __syncthreads();
        #pragma unroll
        for (int k = 0; k < 32; ++k) {
            float4 av = *(const float4*)&As[k][ty*4];
            float4 bv = *(const float4*)&Bs[k][tx*4];
            acc[0][0]+=av.x*bv.x; acc[0][1]+=av.x*bv.y; acc[0][2]+=av.x*bv.z; acc[0][3]+=av.x*bv.w;
            acc[1][0]+=av.y*bv.x; acc[1][1]+=av.y*bv.y; acc[1][2]+=av.y*bv.z; acc[1][3]+=av.y*bv.w;
            acc[2][0]+=av.z*bv.x; acc[2][1]+=av.z*bv.y; acc[2][2]+=av.z*bv.z; acc[2][3]+=av.z*bv.w;
            acc[3][0]+=av.w*bv.x; acc[3][1]+=av.w*bv.y; acc[3][2]+=av.w*bv.z; acc[3][3]+=av.w*bv.w;
        }
    }
    #pragma unroll
    for (int i = 0; i < 4; ++i) {
        const int t = m0 + ty*4 + i;
        float* crow = xg + ((size_t)dir*T_SEQ + t) * G4 + n0 + tx*4;
        #pragma unroll
        for (int j = 0; j < 4; ++j) {
            const int jg = n0 + tx*4 + j;
            crow[j] = acc[i][j] + bi[jg] + bh[jg];
        }
    }
}

// ---------------------------------------------------------------------------
// 2) Bidirectional LSTM, XCD co-location. ROUND 5: SINGLE-WAVE BULK POLL.
//    R0-R4: every compute-delivery variant lands at ~1.5us/step => ring
//    plumbing dominates. Model (consistent with WRITE_SIZE showing agent
//    stores write through to HBM): agent-scope polls are served at the
//    DEVICE coherence point (~500-700cy retry), so per-thread detect lag
//    (up to 1 retry) PLUS the max over 512 independently-polling threads
//    (~another retry) is the bulk of the step. This round:
//      - ONLY WAVE 0 polls: each lane covers 8 h-words via 4 uint64
//        agent-atomic loads per retry (pipelined in flight), loops while
//        any word == SENT. One detect event replaces 512.
//      - wave 0 publishes h to hbuf (2x ds_write_b128, padded layout),
//        B1 releases the block; waves 1-7 sleep in s_barrier instead of
//        VALU-spinning (poll traffic chip-wide drops ~4x).
//      - dot/fold/act/gates/c/h/store are EXACTLY R3 (best, 6.10ms):
//        symmetric waves, shfl left-fold g = xv+P0+...+P7, bit-exact.
// ---------------------------------------------------------------------------
__global__ __attribute__((amdgpu_waves_per_eu(2, 2))) __launch_bounds__(512)
void bilstm_kernel(
    const float* __restrict__ w_hh_f, const float* __restrict__ w_hh_b,
    const float* __restrict__ h0, const float* __restrict__ c0,
    const float* __restrict__ xg,
    uint32_t* __restrict__ h_hist,   // [2][T][HDIM] float bits, pre-set SENT
    int* __restrict__ claim)         // [8] per-XCD rank counters, pre-zeroed
{
    uint32_t xcc;
    asm volatile("s_getreg_b32 %0, hwreg(HW_REG_XCC_ID)" : "=s"(xcc));
    xcc &= 7u;

    __shared__ int rank_s;
    if (threadIdx.x == 0)
        rank_s = __hip_atomic_fetch_add(&claim[xcc], 1, __ATOMIC_RELAXED,
                                        __HIP_MEMORY_SCOPE_AGENT);
    __syncthreads();
    const int rank = rank_s;

    int dir;
    if (xcc == 0) dir = 0;
    else if (xcc == 1) dir = 1;
    else return;
    if (rank >= NBLK) return;
    const int b = rank;

    const int tid = threadIdx.x;    // 512
    const int q   = tid >> 6;       // wave 0..7
    const int l   = tid & 63;       // lane
    const int r   = l >> 3;         // row-in-wave 0..7
    const int i   = l & 7;          // segment index 0..7
    const int gate = r & 3;         // 0=i 1=f 2=g 3=o
    const int huo  = r >> 2;        // 0/1 -> hidden unit 2q+huo
    const int row  = gate * HDIM + b * HSLICE + 2*q + huo;   // global gate row

    // weights: lane dots h[64i .. 64i+63] against w_hh[row][64i..64i+63]
    const float* Wrow = (dir ? w_hh_b : w_hh_f) + (size_t)row * HDIM + i * 64;
    float w[64];
    #pragma unroll
    for (int j = 0; j < 16; ++j) {
        float4 v = ((const float4*)Wrow)[j];
        w[4*j+0]=v.x; w[4*j+1]=v.y; w[4*j+2]=v.z; w[4*j+3]=v.w;
    }
    // Pin weights in VGPRs (R5: 7.17->6.63ms; budget 256 via waves_per_eu(2,2))
    #pragma unroll
    for (int ii = 0; ii < 64; ++ii) asm volatile("" : "+v"(w[ii]));

    // padded, double-buffered h staging: segment s at [buf][68*s .. 68*s+63]
    __shared__ __attribute__((aligned(16))) float hbuf[2][544];

    // c state: lanes 0 and 32 hold c for hidden units 2q and 2q+1
    float c = 0.f;
    if (i == 0 && gate == 0)   // l==0 or l==32
        c = c0[dir*HDIM + b*HSLICE + 2*q + huo];

    const float* xgd = xg + (size_t)dir * T_SEQ * G4;
    uint32_t* hh = h_hist + (size_t)dir * T_SEQ * HDIM;
    const bool leader = (i == 0);

    // preload xg for idx=0 (leader lanes only)
    float xv_cur = 0.f;
    if (leader) {
        const int t0 = dir ? (T_SEQ - 1) : 0;
        xv_cur = xgd[(size_t)t0 * G4 + row];
    }

    // wave-0 poll geometry: lane covers global h words 8l..8l+7
    const int sseg = l >> 3;          // segment of those words
    const int soff = 8 * (l & 7);     // offset within segment

    for (int idx = 0; idx < T_SEQ; ++idx) {
        const int t = dir ? (T_SEQ - 1 - idx) : idx;
        const int p = idx & 1;

        if (q == 0) {
            // -- single-wave bulk poll of all 512 h words --
            float4 va, vb;
            if (idx == 0) {
                const float* hsrc = h0 + dir*HDIM + 8*l;
                va = *(const float4*)(hsrc);
                vb = *(const float4*)(hsrc + 4);
            } else {
                const int tprev = dir ? (t + 1) : (t - 1);
                const uint64_t* wp = (const uint64_t*)(hh + (size_t)tprev*HDIM + 8*l);
                uint64_t u0, u1, u2, u3;
                bool bad;
                do {
                    u0 = __hip_atomic_load(wp + 0, __ATOMIC_RELAXED, __HIP_MEMORY_SCOPE_AGENT);
                    u1 = __hip_atomic_load(wp + 1, __ATOMIC_RELAXED, __HIP_MEMORY_SCOPE_AGENT);
                    u2 = __hip_atomic_load(wp + 2, __ATOMIC_RELAXED, __HIP_MEMORY_SCOPE_AGENT);
                    u3 = __hip_atomic_load(wp + 3, __ATOMIC_RELAXED, __HIP_MEMORY_SCOPE_AGENT);
                    bad = ((uint32_t)u0 == SENT) | ((uint32_t)(u0 >> 32) == SENT)
                        | ((uint32_t)u1 == SENT) | ((uint32_t)(u1 >> 32) == SENT)
                        | ((uint32_t)u2 == SENT) | ((uint32_t)(u2 >> 32) == SENT)
                        | ((uint32_t)u3 == SENT) | ((uint32_t)(u3 >> 32) == SENT);
                } while (__any(bad));
                union { uint64_t u[2]; float4 f; } cva, cvb;
                cva.u[0] = u0; cva.u[1] = u1; cvb.u[0] = u2; cvb.u[1] = u3;
                va = cva.f; vb = cvb.f;
            }
            *(float4*)&hbuf[p][sseg*68 + soff]     = va;
            *(float4*)&hbuf[p][sseg*68 + soff + 4] = vb;
        }
        __syncthreads();                       // B1: h published in LDS

        // prefetch next step's xg (leaders); consumed after next B1
        float xv_nxt = 0.f;
        if (leader && idx + 1 < T_SEQ) {
            const int tn = dir ? (t - 1) : (t + 1);
            xv_nxt = xgd[(size_t)tn * G4 + row];
        }

        // -- per-lane partial: identical FMA chain to R3 --
        const float4* hb4 = (const float4*)&hbuf[p][i*68];
        float s = 0.f;
        #pragma unroll
        for (int j = 0; j < 16; ++j) {
            float4 hvv = hb4[j];               // broadcast across 8 lanes
            s += w[4*j+0]*hvv.x + w[4*j+1]*hvv.y + w[4*j+2]*hvv.z + w[4*j+3]*hvv.w;
        }

        // -- left-fold gather: g = xv + P0 + P1 + ... + P7 (old reduce order)
        const int gbase = l & ~7;              // leader lane of this row group
        float g = xv_cur + s;                  // leader: xv + P0 (s==P0 on leader)
        #pragma unroll
        for (int j = 1; j < 8; ++j) {
            float pj = __shfl(s, gbase + j);
            g += pj;
        }
        // only leaders' g is consumed below.

        // -- activation (same formulas as before) --
        float act = (gate == 2) ? tanhf(g) : 1.f/(1.f + expf(-g));

        // -- gather 4 gates for this wave's 2 hidden units --
        const int base = l & 32;               // 0 for hu 2q, 32 for hu 2q+1
        float iv = __shfl(act, base + 0);
        float fg = __shfl(act, base + 8);
        float gv = __shfl(act, base + 16);
        float ov = __shfl(act, base + 24);

        if ((l & 31) == 0) {                   // lanes 0 and 32
            c = fg*c + iv*gv;
            union { float f; uint32_t u; } hb; hb.f = ov * tanhf(c);
            __hip_atomic_store(hh + (size_t)t*HDIM + b*HSLICE + 2*q + (l>>5), hb.u,
                               __ATOMIC_RELAXED, __HIP_MEMORY_SCOPE_AGENT);
        }
        xv_cur = xv_nxt;
        // hbuf[p] rewrite: wave0 writes hbuf[p] again only after passing
        // B1(idx+1); every reader of hbuf[p] at idx finished its reads
        // before arriving at B1(idx+1). Safe with one barrier per step.
    }
}

// ---------------------------------------------------------------------------
// 3) feats[t][tag] = b_tag[tag] + [hf|hb] . w_tag[tag]
// ---------------------------------------------------------------------------
__global__ __launch_bounds__(256) void feats_kernel(
    const float* __restrict__ h_hist, const float* __restrict__ w_tag,
    const float* __restrict__ b_tag, float* __restrict__ feats)
{
    const int t = blockIdx.x;
    const int tid = threadIdx.x;
    __shared__ __attribute__((aligned(16))) float h[1024];
    __shared__ float partl[192];
    for (int i = tid; i < 512; i += 256) {
        h[i]     = h_hist[(size_t)t*HDIM + i];
        h[512+i] = h_hist[(size_t)T_SEQ*HDIM + (size_t)t*HDIM + i];
    }
    __syncthreads();
    if (tid < 192) {
        const int tag = tid >> 3, p = tid & 7;
        const float* wr = w_tag + (size_t)tag*1024 + p*128;
        const float* hp = h + p*128;
        float s = 0.f;
        #pragma unroll 8
        for (int j = 0; j < 128; ++j) s += wr[j]*hp[j];
        partl[tid] = s;
    }
    __syncthreads();
    if (tid < NTAGS) {
        float s = b_tag[tid];
        #pragma unroll
        for (int p = 0; p < 8; ++p) s += partl[tid*8+p];
        feats[(size_t)t*NTAGS + tid] = s;
    }
}

// ---------------------------------------------------------------------------
// 4) Viterbi forward: single wave, LDS broadcast (R2 version — the R5 shfl
//    rewrite regressed 1.6ms; reverted). Strict > keeps FIRST argmax.
// ---------------------------------------------------------------------------
__global__ void viterbi_fwd_kernel(
    const float* __restrict__ feats, const float* __restrict__ trans,
    float* __restrict__ d_out, unsigned char* __restrict__ bp,
    int* __restrict__ best_tag)
{
    const int lane = threadIdx.x;       // 64 threads = 1 wave
    const bool act = lane < NTAGS;
    float tr[NTAGS];
    #pragma unroll
    for (int p = 0; p < NTAGS; ++p)
        tr[p] = act ? trans[lane*NTAGS + p] : NEGV;

    float fv = (lane == START_TAG) ? 0.f : NEGV;
    __shared__ float fvs[NTAGS];
    __shared__ float term[NTAGS];

    float ftn = act ? feats[lane] : 0.f;   // prefetch t=0
    for (int t = 0; t < T_SEQ; ++t) {
        if (act) fvs[lane] = fv;
        __syncthreads();
        float ft = ftn;
        if (act && t + 1 < T_SEQ) ftn = feats[(size_t)(t+1)*NTAGS + lane];
        float bestv = -3.4e38f;
        int argp = 0;
        #pragma unroll
        for (int p = 0; p < NTAGS; ++p) {
            float sc = tr[p] + fvs[p];
            if (sc > bestv) { bestv = sc; argp = p; }
        }
        __syncthreads();   // reads done before next iteration's write
        fv = bestv + ft;
        if (act) bp[(size_t)t*NTAGS + lane] = (unsigned char)argp;
    }
    if (act) { fv += trans[STOP_TAG*NTAGS + lane]; term[lane] = fv; }
    __syncthreads();
    if (lane == 0) {
        float bv = term[0]; int bi = 0;
        #pragma unroll
        for (int p = 1; p < NTAGS; ++p) if (term[p] > bv) { bv = term[p]; bi = p; }
        d_out[0] = bv;
        *best_tag = bi;
    }
}

// ---------------------------------------------------------------------------
// 5) Hierarchical backtrack
// ---------------------------------------------------------------------------
__global__ void bt_compose_kernel(const unsigned char* __restrict__ bp,
                                  unsigned char* __restrict__ segmap)
{
    const int s = blockIdx.x;
    const int tid = threadIdx.x;   // 64
    __shared__ __attribute__((aligned(16))) unsigned char lbp[64*NTAGS];
    const uint32_t* src = (const uint32_t*)(bp + (size_t)s * 64 * NTAGS);
    uint32_t* dst = (uint32_t*)lbp;
    #pragma unroll
    for (int i = 0; i < 6; ++i) dst[tid + 64*i] = src[tid + 64*i];
    __syncthreads();
    if (tid < NTAGS) {
        int m = tid;
        for (int tt = 63; tt >= 0; --tt) m = lbp[tt*NTAGS + m];
        segmap[s*NTAGS + tid] = (unsigned char)m;
    }
}

__global__ void bt_final_kernel(const unsigned char* __restrict__ segmap,
                                const int* __restrict__ best_tag,
                                int* __restrict__ end_tags)
{
    if (threadIdx.x == 0) {
        int tag = *best_tag;
        end_tags[63] = tag;
        for (int s = 63; s >= 1; --s) {
            tag = segmap[s*NTAGS + tag];
            end_tags[s-1] = tag;
        }
    }
}

__global__ void bt_write_kernel(const unsigned char* __restrict__ bp,
                                const int* __restrict__ end_tags,
                                float* __restrict__ out_path)
{
    const int s = blockIdx.x;
    const int tid = threadIdx.x;   // 64
    __shared__ __attribute__((aligned(16))) unsigned char lbp[64*NTAGS];
    const uint32_t* src = (const uint32_t*)(bp + (size_t)s * 64 * NTAGS);
    uint32_t* dst = (uint32_t*)lbp;
    #pragma unroll
    for (int i = 0; i < 6; ++i) dst[tid + 64*i] = src[tid + 64*i];
    __syncthreads();
    if (tid == 0) {
        int tag = end_tags[s];
        out_path[s*64 + 63] = (float)tag;
        for (int tt = 63; tt >= 1; --tt) {
            tag = lbp[tt*NTAGS + tag];
            out_path[s*64 + tt - 1] = (float)tag;
        }
    }
}

// ---------------------------------------------------------------------------
extern "C" void kernel_launch(void* const* d_in, const int* in_sizes, int n_in,
                              void* d_out, int out_size, void* d_ws, size_t ws_size,
                              hipStream_t stream)
{
    const int*   sent   = (const int*)d_in[0];
    const float* emb    = (const float*)d_in[1];
    const float* w_ih_f = (const float*)d_in[2];
    const float* w_hh_f = (const float*)d_in[3];
    const float* b_ih_f = (const float*)d_in[4];
    const float* b_hh_f = (const float*)d_in[5];
    const float* w_ih_b = (const float*)d_in[6];
    const float* w_hh_b = (const float*)d_in[7];
    const float* b_ih_b = (const float*)d_in[8];
    const float* b_hh_b = (const float*)d_in[9];
    const float* w_tag  = (const float*)d_in[10];
    const float* b_tag  = (const float*)d_in[11];
    const float* trans  = (const float*)d_in[12];
    const float* h0     = (const float*)d_in[13];
    const float* c0     = (const float*)d_in[14];
    float* out = (float*)d_out;

    char* ws = (char*)d_ws;
    size_t off = 0;
    auto alloc = [&](size_t bytes) {
        char* p = ws + off; off += (bytes + 255) & ~(size_t)255; return p;
    };
    float* xg      = (float*)alloc((size_t)2*T_SEQ*G4*sizeof(float));      // 64 MB
    uint32_t* h_hist = (uint32_t*)alloc((size_t)2*T_SEQ*HDIM*sizeof(float)); // 16 MB
    float* feats   = (float*)alloc((size_t)T_SEQ*NTAGS*sizeof(float));
    unsigned char* bp     = (unsigned char*)alloc((size_t)T_SEQ*NTAGS);
    unsigned char* segmap = (unsigned char*)alloc(64*NTAGS);
    int* best_tag = (int*)alloc(sizeof(int));
    int* end_tags = (int*)alloc(64*sizeof(int));
    int* claim    = (int*)alloc(8*sizeof(int));

    if (off > ws_size) {   // diagnostic sentinel: workspace too small
        hipMemsetAsync(d_out, 0xFF, 4, stream);
        return;
    }

    // h_hist = 0xFFFFFFFF sentinel (data-is-the-flag; harness poison is 0xAA)
    hipMemsetAsync(h_hist, 0xFF, (size_t)2*T_SEQ*HDIM*sizeof(float), stream);
    hipMemsetAsync(claim, 0, 8*sizeof(int), stream);

    dim3 gg(G4/64, T_SEQ/64, 2);
    gemm_xg_kernel<<<gg, 256, 0, stream>>>(sent, emb,
        w_ih_f, b_ih_f, b_hh_f, w_ih_b, b_ih_b, b_hh_b, xg);
    bilstm_kernel<<<512, 512, 0, stream>>>(w_hh_f, w_hh_b, h0, c0, xg, h_hist, claim);
    feats_kernel<<<T_SEQ, 256, 0, stream>>>((const float*)h_hist, w_tag, b_tag, feats);
    viterbi_fwd_kernel<<<1, 64, 0, stream>>>(feats, trans, out, bp, best_tag);
    bt_compose_kernel<<<64, 64, 0, stream>>>(bp, segmap);
    bt_final_kernel<<<1, 64, 0, stream>>>(segmap, best_tag, end_tags);
    bt_write_kernel<<<64, 64, 0, stream>>>(bp, end_tags, out + 1);
}

// Round 6
// 16687.437 us; speedup vs baseline: 1.2210x; 1.2210x over previous
//
#include <hip/hip_runtime.h>
#include <cstdint>
#include <cstddef>

#define T_SEQ 4096
#define EMB_D 512
#define HDIM 512
#define G4 2048
#define NTAGS 24
#define START_TAG 22
#define STOP_TAG 23
#define NEGV -10000.0f
#define NBLK 32      // persistent LSTM blocks per direction
#define HSLICE 16    // hidden units per block
#define SENT 0xFFFFFFFFu   // -NaN bit pattern; finite math can't produce it
#define NTILES 4096  // 64 t-tiles x 2 dirs x 32 j-tiles

// ---------------------------------------------------------------------------
// FUSED kernel. ROUND 6: R5's single-wave bulk poll was a 3x regression
// (FETCH 46->120MB from coupled retries; per-thread parallel polling is the
// right detection structure). bilstm is reverted to EXACT R3 (best, 6.10ms).
// New: the xg GEMM no longer runs as a serial prologue kernel. Blocks on
// XCD2-7 (192 CUs that previously exited) drain an atomic tile queue,
// prioritized in recurrence order (fwd t ascending / bwd t descending), and
// publish xg with agent-scope stores. LSTM leaders consume xg through the
// same data-is-the-flag sentinel machinery as h_hist (xg pre-memset 0xFF);
// steady-state cost is one compare per prefetched word since the worker pool
// runs ~3 orders of magnitude ahead of the recurrence. XCD0/1 keep zero
// worker blocks (non-participants there exit) so the h-ring is undisturbed.
// Worker accumulation order = original gemm kernel (k ascending) -> bit-exact.
// ---------------------------------------------------------------------------
__global__ __attribute__((amdgpu_waves_per_eu(2, 2))) __launch_bounds__(512)
void fused_kernel(
    const int* __restrict__ sent, const float* __restrict__ emb,
    const float* __restrict__ w_ih_f, const float* __restrict__ b_ih_f, const float* __restrict__ b_hh_f,
    const float* __restrict__ w_ih_b, const float* __restrict__ b_ih_b, const float* __restrict__ b_hh_b,
    const float* __restrict__ w_hh_f, const float* __restrict__ w_hh_b,
    const float* __restrict__ h0, const float* __restrict__ c0,
    uint32_t* __restrict__ xg,       // [2][T][G4] float bits, pre-set SENT
    uint32_t* __restrict__ h_hist,   // [2][T][HDIM] float bits, pre-set SENT
    int* __restrict__ claim,         // [8] per-XCD rank counters, pre-zeroed
    int* __restrict__ tilectr)       // [1] gemm tile queue head, pre-zeroed
{
    // 16 KB shared, dual-purpose: workers use As/Bs (2x 32x64 tiles);
    // participants use hbuf double-buffer (2 x 544 floats, 68-stride pad).
    __shared__ __attribute__((aligned(16))) float smem[4096];
    __shared__ int rank_s;
    __shared__ int g_s;

    uint32_t xcc;
    asm volatile("s_getreg_b32 %0, hwreg(HW_REG_XCC_ID)" : "=s"(xcc));
    xcc &= 7u;
    const int tid = threadIdx.x;    // 512

    if (tid == 0)
        rank_s = __hip_atomic_fetch_add(&claim[xcc], 1, __ATOMIC_RELAXED,
                                        __HIP_MEMORY_SCOPE_AGENT);
    __syncthreads();
    const int rank = rank_s;

    if (xcc >= 2) {
        // ---------------- GEMM worker (XCD2-7 only) ----------------
        float* As = smem;          // As[k][t] at smem[k*64+t]
        float* Bs = smem + 2048;   // Bs[k][j]
        const int lrow = tid >> 3;          // 0..63
        const int lk4  = (tid & 7) * 4;     // 0,4,...,28
        const int ty = tid >> 5;            // 0..15 (M/4)
        const int tx = tid & 31;            // 0..31 (N/2)
        for (;;) {
            if (tid == 0)
                g_s = __hip_atomic_fetch_add(tilectr, 1, __ATOMIC_RELAXED,
                                             __HIP_MEMORY_SCOPE_AGENT);
            __syncthreads();
            const int g = g_s;
            if (g >= NTILES) break;
            // priority decode: tile band tt serves fwd t-tile tt AND bwd
            // t-tile 63-tt; both directions' first-needed tiles are g=0..63.
            const int tt  = g >> 6;
            const int dir = (g >> 5) & 1;
            const int jt  = g & 31;
            const int mt  = dir ? (63 - tt) : tt;
            const int m0 = mt * 64, n0 = jt * 64;
            const float* W  = dir ? w_ih_b : w_ih_f;
            const float* bi = dir ? b_ih_b : b_ih_f;
            const float* bh = dir ? b_hh_b : b_hh_f;
            const int srow = sent[m0 + lrow];
            const float* aptr = emb + (size_t)srow * EMB_D + lk4;
            const float* bptr = W   + (size_t)(n0 + lrow) * EMB_D + lk4;
            float acc[4][2];
            #pragma unroll
            for (int i2 = 0; i2 < 4; ++i2) { acc[i2][0] = 0.f; acc[i2][1] = 0.f; }
            for (int kk = 0; kk < EMB_D; kk += 32) {
                float4 a  = *(const float4*)(aptr + kk);
                float4 bv = *(const float4*)(bptr + kk);
                __syncthreads();   // prev compute done before overwrite
                As[(lk4+0)*64+lrow]=a.x;  As[(lk4+1)*64+lrow]=a.y;
                As[(lk4+2)*64+lrow]=a.z;  As[(lk4+3)*64+lrow]=a.w;
                Bs[(lk4+0)*64+lrow]=bv.x; Bs[(lk4+1)*64+lrow]=bv.y;
                Bs[(lk4+2)*64+lrow]=bv.z; Bs[(lk4+3)*64+lrow]=bv.w;
                __syncthreads();
                #pragma unroll
                for (int k = 0; k < 32; ++k) {
                    float4 av = *(const float4*)&As[k*64 + ty*4];
                    float2 bb = *(const float2*)&Bs[k*64 + tx*2];
                    acc[0][0]+=av.x*bb.x; acc[0][1]+=av.x*bb.y;
                    acc[1][0]+=av.y*bb.x; acc[1][1]+=av.y*bb.y;
                    acc[2][0]+=av.z*bb.x; acc[2][1]+=av.z*bb.y;
                    acc[3][0]+=av.w*bb.x; acc[3][1]+=av.w*bb.y;
                }
            }
            #pragma unroll
            for (int i2 = 0; i2 < 4; ++i2) {
                const int t = m0 + ty*4 + i2;
                uint32_t* crow = xg + ((size_t)dir*T_SEQ + t) * G4 + n0 + tx*2;
                const int jg = n0 + tx*2;
                union { float f; uint32_t u; } v0, v1;
                v0.f = acc[i2][0] + bi[jg]   + bh[jg];
                v1.f = acc[i2][1] + bi[jg+1] + bh[jg+1];
                // agent-scope stores: visible to cross-XCD sentinel polls
                __hip_atomic_store(crow + 0, v0.u, __ATOMIC_RELAXED, __HIP_MEMORY_SCOPE_AGENT);
                __hip_atomic_store(crow + 1, v1.u, __ATOMIC_RELAXED, __HIP_MEMORY_SCOPE_AGENT);
            }
            // g_s rewrite for next tile is safe: tid0 can only pass the kk
            // loop's barriers after every thread has read g for this tile.
        }
        return;
    }

    // ---------------- LSTM participant (exact R3 body + xg sentinel) ------
    if (rank >= NBLK) return;     // keep XCD0/1 free of worker traffic
    const int dir = (int)xcc;     // 0 or 1
    const int b = rank;

    const int q   = tid >> 6;       // wave 0..7
    const int l   = tid & 63;       // lane
    const int r   = l >> 3;         // row-in-wave 0..7
    const int i   = l & 7;          // segment index 0..7
    const int gate = r & 3;         // 0=i 1=f 2=g 3=o
    const int huo  = r >> 2;        // 0/1 -> hidden unit 2q+huo
    const int row  = gate * HDIM + b * HSLICE + 2*q + huo;   // global gate row

    // weights: lane dots h[64i .. 64i+63] against w_hh[row][64i..64i+63]
    const float* Wrow = (dir ? w_hh_b : w_hh_f) + (size_t)row * HDIM + i * 64;
    float w[64];
    #pragma unroll
    for (int j = 0; j < 16; ++j) {
        float4 v = ((const float4*)Wrow)[j];
        w[4*j+0]=v.x; w[4*j+1]=v.y; w[4*j+2]=v.z; w[4*j+3]=v.w;
    }
    // Pin weights in VGPRs (R5: 7.17->6.63ms; budget 256 via waves_per_eu(2,2))
    #pragma unroll
    for (int ii = 0; ii < 64; ++ii) asm volatile("" : "+v"(w[ii]));

    // c state: lanes 0 and 32 hold c for hidden units 2q and 2q+1
    float c = 0.f;
    if (i == 0 && gate == 0)   // l==0 or l==32
        c = c0[dir*HDIM + b*HSLICE + 2*q + huo];

    const uint32_t* xgu = xg + (size_t)dir * T_SEQ * G4;
    uint32_t* hh = h_hist + (size_t)dir * T_SEQ * HDIM;
    const bool leader = (i == 0);

    // preload xg for idx=0 (leaders); tile priority 0 -> ready in ~10us
    uint32_t xu_cur = 0;
    const uint32_t* xp_cur = xgu;
    if (leader) {
        const int t0 = dir ? (T_SEQ - 1) : 0;
        xp_cur = xgu + (size_t)t0 * G4 + row;
        xu_cur = __hip_atomic_load(xp_cur, __ATOMIC_RELAXED, __HIP_MEMORY_SCOPE_AGENT);
    }

    for (int idx = 0; idx < T_SEQ; ++idx) {
        const int t = dir ? (T_SEQ - 1 - idx) : idx;
        float* hb = smem + (idx & 1) * 544;   // padded double buffer

        // -- poll h[t-1][tid] (one value per thread, data-is-the-flag) --
        float hv;
        if (idx == 0) {
            hv = h0[dir*HDIM + tid];
        } else {
            const int tprev = dir ? (t + 1) : (t - 1);
            const uint32_t* wp = hh + (size_t)tprev*HDIM + tid;
            uint32_t u;
            do {
                u = __hip_atomic_load(wp, __ATOMIC_RELAXED, __HIP_MEMORY_SCOPE_AGENT);
            } while (u == SENT);
            union { uint32_t uu; float f; } cv; cv.uu = u;
            hv = cv.f;
        }
        hb[q*68 + l] = hv;
        __syncthreads();                       // B1: h published in LDS

        // resolve this step's xg (retry only if GEMM hasn't produced it yet;
        // never taken after the first few steps)
        float xv_cur = 0.f;
        if (leader) {
            while (xu_cur == SENT)
                xu_cur = __hip_atomic_load(xp_cur, __ATOMIC_RELAXED, __HIP_MEMORY_SCOPE_AGENT);
            xv_cur = __uint_as_float(xu_cur);
        }
        // prefetch next step's xg (checked at next step's resolve)
        if (leader && idx + 1 < T_SEQ) {
            const int tn = dir ? (t - 1) : (t + 1);
            xp_cur = xgu + (size_t)tn * G4 + row;
            xu_cur = __hip_atomic_load(xp_cur, __ATOMIC_RELAXED, __HIP_MEMORY_SCOPE_AGENT);
        }

        // -- per-lane partial: identical FMA chain to R3 --
        const float4* hb4 = (const float4*)&hb[i*68];
        float s = 0.f;
        #pragma unroll
        for (int j = 0; j < 16; ++j) {
            float4 hvv = hb4[j];               // broadcast across 8 lanes
            s += w[4*j+0]*hvv.x + w[4*j+1]*hvv.y + w[4*j+2]*hvv.z + w[4*j+3]*hvv.w;
        }

        // -- left-fold gather: g = xv + P0 + P1 + ... + P7 (R3 order) --
        const int gbase = l & ~7;              // leader lane of this row group
        float g = xv_cur + s;                  // leader: xv + P0
        #pragma unroll
        for (int j = 1; j < 8; ++j) {
            float pj = __shfl(s, gbase + j);
            g += pj;
        }
        // only leaders' g is consumed below.

        // -- activation (same formulas) --
        float act = (gate == 2) ? tanhf(g) : 1.f/(1.f + expf(-g));

        // -- gather 4 gates for this wave's 2 hidden units --
        const int base = l & 32;               // 0 for hu 2q, 32 for hu 2q+1
        float iv = __shfl(act, base + 0);
        float fg = __shfl(act, base + 8);
        float gv = __shfl(act, base + 16);
        float ov = __shfl(act, base + 24);

        if ((l & 31) == 0) {                   // lanes 0 and 32
            c = fg*c + iv*gv;
            union { float f; uint32_t u; } hbv; hbv.f = ov * tanhf(c);
            __hip_atomic_store(hh + (size_t)t*HDIM + b*HSLICE + 2*q + (l>>5), hbv.u,
                               __ATOMIC_RELAXED, __HIP_MEMORY_SCOPE_AGENT);
        }
        // hbuf[p] rewrite at idx+2 gated by B1(idx+1); readers of hbuf[p] at
        // idx finished before arriving there. One barrier per step.
    }
}

// ---------------------------------------------------------------------------
// 3) feats[t][tag] = b_tag[tag] + [hf|hb] . w_tag[tag]
// ---------------------------------------------------------------------------
__global__ __launch_bounds__(256) void feats_kernel(
    const float* __restrict__ h_hist, const float* __restrict__ w_tag,
    const float* __restrict__ b_tag, float* __restrict__ feats)
{
    const int t = blockIdx.x;
    const int tid = threadIdx.x;
    __shared__ __attribute__((aligned(16))) float h[1024];
    __shared__ float partl[192];
    for (int i = tid; i < 512; i += 256) {
        h[i]     = h_hist[(size_t)t*HDIM + i];
        h[512+i] = h_hist[(size_t)T_SEQ*HDIM + (size_t)t*HDIM + i];
    }
    __syncthreads();
    if (tid < 192) {
        const int tag = tid >> 3, p = tid & 7;
        const float* wr = w_tag + (size_t)tag*1024 + p*128;
        const float* hp = h + p*128;
        float s = 0.f;
        #pragma unroll 8
        for (int j = 0; j < 128; ++j) s += wr[j]*hp[j];
        partl[tid] = s;
    }
    __syncthreads();
    if (tid < NTAGS) {
        float s = b_tag[tid];
        #pragma unroll
        for (int p = 0; p < 8; ++p) s += partl[tid*8+p];
        feats[(size_t)t*NTAGS + tid] = s;
    }
}

// ---------------------------------------------------------------------------
// 4) Viterbi forward: single wave, LDS broadcast. Strict > keeps FIRST argmax.
// ---------------------------------------------------------------------------
__global__ void viterbi_fwd_kernel(
    const float* __restrict__ feats, const float* __restrict__ trans,
    float* __restrict__ d_out, unsigned char* __restrict__ bp,
    int* __restrict__ best_tag)
{
    const int lane = threadIdx.x;       // 64 threads = 1 wave
    const bool act = lane < NTAGS;
    float tr[NTAGS];
    #pragma unroll
    for (int p = 0; p < NTAGS; ++p)
        tr[p] = act ? trans[lane*NTAGS + p] : NEGV;

    float fv = (lane == START_TAG) ? 0.f : NEGV;
    __shared__ float fvs[NTAGS];
    __shared__ float term[NTAGS];

    float ftn = act ? feats[lane] : 0.f;   // prefetch t=0
    for (int t = 0; t < T_SEQ; ++t) {
        if (act) fvs[lane] = fv;
        __syncthreads();
        float ft = ftn;
        if (act && t + 1 < T_SEQ) ftn = feats[(size_t)(t+1)*NTAGS + lane];
        float bestv = -3.4e38f;
        int argp = 0;
        #pragma unroll
        for (int p = 0; p < NTAGS; ++p) {
            float sc = tr[p] + fvs[p];
            if (sc > bestv) { bestv = sc; argp = p; }
        }
        __syncthreads();   // reads done before next iteration's write
        fv = bestv + ft;
        if (act) bp[(size_t)t*NTAGS + lane] = (unsigned char)argp;
    }
    if (act) { fv += trans[STOP_TAG*NTAGS + lane]; term[lane] = fv; }
    __syncthreads();
    if (lane == 0) {
        float bv = term[0]; int bi = 0;
        #pragma unroll
        for (int p = 1; p < NTAGS; ++p) if (term[p] > bv) { bv = term[p]; bi = p; }
        d_out[0] = bv;
        *best_tag = bi;
    }
}

// ---------------------------------------------------------------------------
// 5) Hierarchical backtrack
// ---------------------------------------------------------------------------
__global__ void bt_compose_kernel(const unsigned char* __restrict__ bp,
                                  unsigned char* __restrict__ segmap)
{
    const int s = blockIdx.x;
    const int tid = threadIdx.x;   // 64
    __shared__ __attribute__((aligned(16))) unsigned char lbp[64*NTAGS];
    const uint32_t* src = (const uint32_t*)(bp + (size_t)s * 64 * NTAGS);
    uint32_t* dst = (uint32_t*)lbp;
    #pragma unroll
    for (int i = 0; i < 6; ++i) dst[tid + 64*i] = src[tid + 64*i];
    __syncthreads();
    if (tid < NTAGS) {
        int m = tid;
        for (int tt = 63; tt >= 0; --tt) m = lbp[tt*NTAGS + m];
        segmap[s*NTAGS + tid] = (unsigned char)m;
    }
}

__global__ void bt_final_kernel(const unsigned char* __restrict__ segmap,
                                const int* __restrict__ best_tag,
                                int* __restrict__ end_tags)
{
    if (threadIdx.x == 0) {
        int tag = *best_tag;
        end_tags[63] = tag;
        for (int s = 63; s >= 1; --s) {
            tag = segmap[s*NTAGS + tag];
            end_tags[s-1] = tag;
        }
    }
}

__global__ void bt_write_kernel(const unsigned char* __restrict__ bp,
                                const int* __restrict__ end_tags,
                                float* __restrict__ out_path)
{
    const int s = blockIdx.x;
    const int tid = threadIdx.x;   // 64
    __shared__ __attribute__((aligned(16))) unsigned char lbp[64*NTAGS];
    const uint32_t* src = (const uint32_t*)(bp + (size_t)s * 64 * NTAGS);
    uint32_t* dst = (uint32_t*)lbp;
    #pragma unroll
    for (int i = 0; i < 6; ++i) dst[tid + 64*i] = src[tid + 64*i];
    __syncthreads();
    if (tid == 0) {
        int tag = end_tags[s];
        out_path[s*64 + 63] = (float)tag;
        for (int tt = 63; tt >= 1; --tt) {
            tag = lbp[tt*NTAGS + tag];
            out_path[s*64 + tt - 1] = (float)tag;
        }
    }
}

// ---------------------------------------------------------------------------
extern "C" void kernel_launch(void* const* d_in, const int* in_sizes, int n_in,
                              void* d_out, int out_size, void* d_ws, size_t ws_size,
                              hipStream_t stream)
{
    const int*   sent   = (const int*)d_in[0];
    const float* emb    = (const float*)d_in[1];
    const float* w_ih_f = (const float*)d_in[2];
    const float* w_hh_f = (const float*)d_in[3];
    const float* b_ih_f = (const float*)d_in[4];
    const float* b_hh_f = (const float*)d_in[5];
    const float* w_ih_b = (const float*)d_in[6];
    const float* w_hh_b = (const float*)d_in[7];
    const float* b_ih_b = (const float*)d_in[8];
    const float* b_hh_b = (const float*)d_in[9];
    const float* w_tag  = (const float*)d_in[10];
    const float* b_tag  = (const float*)d_in[11];
    const float* trans  = (const float*)d_in[12];
    const float* h0     = (const float*)d_in[13];
    const float* c0     = (const float*)d_in[14];
    float* out = (float*)d_out;

    char* ws = (char*)d_ws;
    size_t off = 0;
    auto alloc = [&](size_t bytes) {
        char* p = ws + off; off += (bytes + 255) & ~(size_t)255; return p;
    };
    uint32_t* xg     = (uint32_t*)alloc((size_t)2*T_SEQ*G4*sizeof(float));   // 64 MB
    uint32_t* h_hist = (uint32_t*)alloc((size_t)2*T_SEQ*HDIM*sizeof(float)); // 16 MB
    float* feats   = (float*)alloc((size_t)T_SEQ*NTAGS*sizeof(float));
    unsigned char* bp     = (unsigned char*)alloc((size_t)T_SEQ*NTAGS);
    unsigned char* segmap = (unsigned char*)alloc(64*NTAGS);
    int* best_tag = (int*)alloc(sizeof(int));
    int* end_tags = (int*)alloc(64*sizeof(int));
    int* claim    = (int*)alloc(8*sizeof(int));
    int* tilectr  = (int*)alloc(sizeof(int));

    if (off > ws_size) {   // diagnostic sentinel: workspace too small
        hipMemsetAsync(d_out, 0xFF, 4, stream);
        return;
    }

    // data-is-the-flag sentinels (harness poison is 0xAA)
    hipMemsetAsync(xg,     0xFF, (size_t)2*T_SEQ*G4*sizeof(float), stream);
    hipMemsetAsync(h_hist, 0xFF, (size_t)2*T_SEQ*HDIM*sizeof(float), stream);
    hipMemsetAsync(claim, 0, 8*sizeof(int), stream);
    hipMemsetAsync(tilectr, 0, sizeof(int), stream);

    fused_kernel<<<512, 512, 0, stream>>>(
        sent, emb,
        w_ih_f, b_ih_f, b_hh_f, w_ih_b, b_ih_b, b_hh_b,
        w_hh_f, w_hh_b, h0, c0,
        xg, h_hist, claim, tilectr);
    feats_kernel<<<T_SEQ, 256, 0, stream>>>((const float*)h_hist, w_tag, b_tag, feats);
    viterbi_fwd_kernel<<<1, 64, 0, stream>>>(feats, trans, out, bp, best_tag);
    bt_compose_kernel<<<64, 64, 0, stream>>>(bp, segmap);
    bt_final_kernel<<<1, 64, 0, stream>>>(segmap, best_tag, end_tags);
    bt_write_kernel<<<64, 64, 0, stream>>>(bp, end_tags, out + 1);
}